// Round 11
// baseline (46.593 us; speedup 1.0000x reference)
//
#include <hip/hip_runtime.h>
#include <hip/hip_bf16.h>
#include <math.h>

typedef __bf16 bf16;
typedef __bf16 bf16x8 __attribute__((ext_vector_type(8)));
typedef float  f32x4  __attribute__((ext_vector_type(4)));

static constexpr int kTokens = 32768;   // B*S = 8*4096
static constexpr int kH   = 768;
static constexpr int kC   = 64;
static constexpr int kCK  = 64;         // K-chunk (A rows = 256 B, power of 2)
static constexpr int kNQ  = kH / kCK;   // 12 chunks
static constexpr int kTB  = 64;         // tokens per block (4 waves x 16)
static constexpr int kBW  = 72;         // B lds row stride (144 B: 2-way banks = free)
static constexpr unsigned kProducers = 25;

// ---- issue one A-chunk (64 rows x 256 B) via global_load_lds, src pre-swizzled ----
// LDS dest is linear (wave-uniform base + lane*16); element (row,k) of the chunk ends
// up at byte (row*256) + ((k*4) ^ ((row&7)<<4)); readers apply the same XOR.
__device__ __forceinline__ void issue_a(const float* __restrict__ hs_blk, int q,
                                        float* __restrict__ buf, int wv, int lane) {
    #pragma unroll
    for (int r = 0; r < 4; ++r) {
        const int span   = wv * 4 + r;            // 0..15, 4 rows (1 KB) per issue
        const int absrow = span * 4 + (lane >> 4);
        const int colB   = (lane & 15) * 16;
        const int scol   = colB ^ ((absrow & 7) << 4);
        const char* src  = (const char*)(hs_blk + (size_t)absrow * kH + q * kCK) + scol;
        float* dst = buf + span * 256;            // wave-uniform
        __builtin_amdgcn_global_load_lds(
            (const __attribute__((address_space(1))) void*)src,
            (__attribute__((address_space(3))) void*)dst, 16, 0, 0);
    }
}

// ---------- fused: distributed prep + relaxed-poll grid barrier + R7 main ----------
// 512 blocks x 256 thr, 58.8 KB LDS -> exactly 2 blocks/CU: all 512 co-resident,
// spin barrier cannot deadlock. Poll uses RELAXED agent loads (no L2 invalidate);
// exactly ONE release-wbl2 per producer block and ONE acquire fence per block.
__global__ __launch_bounds__(256, 2) void incong_fused(
    const float* __restrict__ hs,      // [kTokens][kH] f32
    const float* __restrict__ W_ct, const float* __restrict__ b_ct,
    const float* __restrict__ W_cd, const float* __restrict__ b_cd,
    const float* __restrict__ W_e1, const float* __restrict__ b_e1,
    const float* __restrict__ W_e2, const float* __restrict__ b_e2,
    bf16* __restrict__ Wt,             // ws: [65][kH] bf16
    float* __restrict__ bsc_p,         // ws scalar
    unsigned* __restrict__ flag,       // ws counter (memset to 0 each call)
    float* __restrict__ out)           // [3][kTokens]
{
    __shared__ float lds_a[2][kTB][kCK];   // 2 x 16 KB, rows 256 B, no pad (swizzled)
    __shared__ bf16  lds_w[65][kBW];       // 9.4 KB
    __shared__ float t[64][65];            // prep transpose tile (16.6 KB)

    const int tid  = threadIdx.x;
    const int lane = tid & 63;
    const int wv   = tid >> 6;         // 0..3: 16-token tile within block
    const int r16  = lane & 15;
    const int kg   = lane >> 4;        // 0..3
    const int b    = blockIdx.x;

    const int tok0 = b * kTB;
    const float* hs_blk = hs + (size_t)tok0 * kH;

    // A(0) prefetch issues BEFORE the prep wait: HBM latency hides under it.
    issue_a(hs_blk, 0, &lds_a[0][0][0], wv, lane);

    // ---- distributed prep (blocks 0..24) ----
    if (b < 12) {                                  // transpose one 64x64 tile of W_e1
        const int k0 = b * 64;
        #pragma unroll
        for (int i = 0; i < 16; ++i) {
            int idx = tid + i * 256;
            int k = idx >> 6, n = idx & 63;
            t[k][n] = W_e1[(size_t)(k0 + k) * kC + n];
        }
        __syncthreads();
        #pragma unroll
        for (int i = 0; i < 16; ++i) {
            int idx = tid + i * 256;
            int n = idx >> 6, k = idx & 63;
            Wt[(size_t)n * kH + k0 + k] = (bf16)t[k][n];
        }
    } else if (b < 24) {                           // w_sc chunk = W_ct @ W_cd
        const int k0 = (b - 12) * 64;
        #pragma unroll
        for (int i = 0; i < 16; ++i) {
            int idx = tid + i * 256;
            int k = idx >> 6, c = idx & 63;
            t[k][c] = W_ct[(size_t)(k0 + k) * kC + c];
        }
        __syncthreads();
        if (tid < 64) {
            float s = 0.f;
            #pragma unroll
            for (int c = 0; c < kC; ++c) s += t[tid][c] * W_cd[c];
            Wt[(size_t)kC * kH + k0 + tid] = (bf16)s;
        }
    } else if (b == 24) {
        if (tid < 64) {
            float v = b_ct[tid] * W_cd[tid];
            #pragma unroll
            for (int m = 1; m < 64; m <<= 1) v += __shfl_xor(v, m);
            if (tid == 0) bsc_p[0] = v + b_cd[0];
        }
    }
    if (b < (int)kProducers) {
        __syncthreads();                           // block's stores retired in L2
        if (tid == 0)                              // ONE release (wbl2) per producer
            __hip_atomic_fetch_add(flag, 1u, __ATOMIC_RELEASE, __HIP_MEMORY_SCOPE_AGENT);
    }
    // ---- grid barrier: RELAXED polling (no cache maintenance per iteration) ----
    if (tid == 0) {
        while (__hip_atomic_load(flag, __ATOMIC_RELAXED, __HIP_MEMORY_SCOPE_AGENT) < kProducers)
            __builtin_amdgcn_s_sleep(16);
    }
    __syncthreads();
    __builtin_amdgcn_fence(__ATOMIC_ACQUIRE, "agent");   // single inv, then read Wt

    // ---- main (R7 body verbatim) ----
    f32x4 acc[5];
    #pragma unroll
    for (int n = 0; n < 5; ++n) acc[n] = (f32x4){0.f, 0.f, 0.f, 0.f};

    const int      trow  = wv * 16 + r16;
    const unsigned sw    = (unsigned)((r16 & 7) << 4);
    const char*    ab0   = (const char*)&lds_a[0][trow][0];
    const char*    ab1   = (const char*)&lds_a[1][trow][0];

    for (int q = 0; q < kNQ; ++q) {
        const int pb = q & 1;
        // ---- stage B chunk q (loads then writes; compiler's vmcnt before the
        //      ds_write drains A(q) exactly, leaving A(q+1) outstanding) ----
        {
            const int c0 = tid, c1 = tid + 256;
            const int row0 = c0 >> 3, col0 = (c0 & 7) * 8;
            const int row1 = c1 >> 3, col1 = (c1 & 7) * 8;
            bf16x8 v0 = *reinterpret_cast<const bf16x8*>(&Wt[(size_t)row0 * kH + q * kCK + col0]);
            bf16x8 v1 = *reinterpret_cast<const bf16x8*>(&Wt[(size_t)row1 * kH + q * kCK + col1]);
            bf16x8 v2;
            if (tid < 8) v2 = *reinterpret_cast<const bf16x8*>(&Wt[(size_t)64 * kH + q * kCK + tid * 8]);
            if (q + 1 < kNQ) issue_a(hs_blk, q + 1, &lds_a[pb ^ 1][0][0], wv, lane);
            *reinterpret_cast<bf16x8*>(&lds_w[row0][col0]) = v0;
            *reinterpret_cast<bf16x8*>(&lds_w[row1][col1]) = v1;
            if (tid < 8) *reinterpret_cast<bf16x8*>(&lds_w[64][tid * 8]) = v2;
        }
        asm volatile("s_waitcnt lgkmcnt(0)" ::: "memory");
        __builtin_amdgcn_s_barrier();
        asm volatile("" ::: "memory");

        // ---- compute chunk q: swizzled A reads + MFMA ----
        const char* abase = pb ? ab1 : ab0;
        #pragma unroll
        for (int s = 0; s < 2; ++s) {
            const unsigned o = (unsigned)(s * 128 + kg * 32);
            const f32x4 a0 = *reinterpret_cast<const f32x4*>(abase + (o ^ sw));
            const f32x4 a1 = *reinterpret_cast<const f32x4*>(abase + ((o + 16u) ^ sw));
            bf16x8 af;
            af[0] = (bf16)a0[0]; af[1] = (bf16)a0[1]; af[2] = (bf16)a0[2]; af[3] = (bf16)a0[3];
            af[4] = (bf16)a1[0]; af[5] = (bf16)a1[1]; af[6] = (bf16)a1[2]; af[7] = (bf16)a1[3];
            #pragma unroll
            for (int n = 0; n < 4; ++n) {
                const bf16x8 bfr = *reinterpret_cast<const bf16x8*>(
                    &lds_w[n * 16 + r16][s * 32 + kg * 8]);
                acc[n] = __builtin_amdgcn_mfma_f32_16x16x32_bf16(af, bfr, acc[n], 0, 0, 0);
            }
            {
                const bf16x8 b4 = *reinterpret_cast<const bf16x8*>(&lds_w[64][s * 32 + kg * 8]);
                acc[4] = __builtin_amdgcn_mfma_f32_16x16x32_bf16(af, b4, acc[4], 0, 0, 0);
            }
        }
        asm volatile("" ::: "memory");
        __builtin_amdgcn_s_barrier();      // all waves done reading before next overwrite
    }

    // ---- epilogue (per wave; D layout: col = lane&15, row = kg*4 + reg) ----
    float part[4] = {0.f, 0.f, 0.f, 0.f};
    #pragma unroll
    for (int n = 0; n < 4; ++n) {
        const int cidx = n * 16 + r16;
        const float be = b_e1[cidx];
        const float we = W_e2[cidx];
        #pragma unroll
        for (int r = 0; r < 4; ++r)
            part[r] += fmaxf(acc[n][r] + be, 0.f) * we;
    }
    #pragma unroll
    for (int m = 1; m < 16; m <<= 1) {
        #pragma unroll
        for (int r = 0; r < 4; ++r) part[r] += __shfl_xor(part[r], m);
    }
    if (r16 == 0) {
        const float bsc = bsc_p[0];
        const float be2 = b_e2[0];
        #pragma unroll
        for (int r = 0; r < 4; ++r) {
            const int tok = tok0 + wv * 16 + kg * 4 + r;
            const float sc = acc[4][r] + bsc;          // sc column accumulator
            out[tok]               = 1.f / (1.f + __expf(-sc));
            out[kTokens + tok]     = 1.f / (1.f + __expf(-(part[r] + be2)));
            out[2 * kTokens + tok] = 1.f / 4096.f;     // mean of softmax == 1/S
        }
    }
}

extern "C" void kernel_launch(void* const* d_in, const int* in_sizes, int n_in,
                              void* d_out, int out_size, void* d_ws, size_t ws_size,
                              hipStream_t stream) {
    const float* hs   = (const float*)d_in[0];
    // d_in[1] = attention_mask (all ones, unused by the reference math)
    const float* W_ct = (const float*)d_in[2];
    const float* b_ct = (const float*)d_in[3];
    const float* W_cd = (const float*)d_in[4];
    const float* b_cd = (const float*)d_in[5];
    const float* W_e1 = (const float*)d_in[6];
    const float* b_e1 = (const float*)d_in[7];
    const float* W_e2 = (const float*)d_in[8];
    const float* b_e2 = (const float*)d_in[9];
    // d_in[10..13] = W_q, b_q, W_k, b_k — unused (surprise is exactly 1/S)

    bf16*     Wt   = (bf16*)d_ws;
    float*    bsc  = (float*)((char*)d_ws + (size_t)80 * kH * sizeof(bf16));
    unsigned* flag = (unsigned*)((char*)d_ws + 256 * 1024);

    hipMemsetAsync(flag, 0, sizeof(unsigned), stream);   // reset barrier each call

    incong_fused<<<kTokens / kTB, 256, 0, stream>>>(
        hs, W_ct, b_ct, W_cd, b_cd, W_e1, b_e1, W_e2, b_e2,
        Wt, bsc, flag, (float*)d_out);
}

// Round 12
// 30.180 us; speedup vs baseline: 1.5439x; 1.5439x over previous
//
#include <hip/hip_runtime.h>
#include <hip/hip_bf16.h>
#include <math.h>

typedef __bf16 bf16;
typedef __bf16 bf16x8 __attribute__((ext_vector_type(8)));
typedef float  f32x4  __attribute__((ext_vector_type(4)));

static constexpr int kTokens = 32768;   // B*S = 8*4096
static constexpr int kH   = 768;
static constexpr int kC   = 64;
static constexpr int kCK  = 64;         // K-chunk (A rows = 256 B, power of 2)
static constexpr int kNQ  = kH / kCK;   // 12 chunks
static constexpr int kTB  = 128;        // tokens per block (8 waves x 16) -> B traffic halved
static constexpr int kBW  = 72;         // B lds row stride (144 B: 2-way banks = free)

// ---------- prep (all-coalesced): Wt[n][k]=W_e1^T, row 64 = w_sc = W_ct@W_cd ----------
__global__ __launch_bounds__(256) void prep_kernel(
    const float* __restrict__ W_ct, const float* __restrict__ b_ct,
    const float* __restrict__ W_cd, const float* __restrict__ b_cd,
    const float* __restrict__ W_e1, bf16* __restrict__ Wt,
    float* __restrict__ bsc) {
    __shared__ float t[64][65];
    const int tid = threadIdx.x;
    const int b   = blockIdx.x;
    if (b < 12) {
        const int k0 = b * 64;
        #pragma unroll
        for (int i = 0; i < 16; ++i) {
            int idx = tid + i * 256;
            int k = idx >> 6, n = idx & 63;
            t[k][n] = W_e1[(size_t)(k0 + k) * kC + n];
        }
        __syncthreads();
        #pragma unroll
        for (int i = 0; i < 16; ++i) {
            int idx = tid + i * 256;
            int n = idx >> 6, k = idx & 63;
            Wt[(size_t)n * kH + k0 + k] = (bf16)t[k][n];
        }
    } else if (b < 24) {
        const int k0 = (b - 12) * 64;
        #pragma unroll
        for (int i = 0; i < 16; ++i) {
            int idx = tid + i * 256;
            int k = idx >> 6, c = idx & 63;
            t[k][c] = W_ct[(size_t)(k0 + k) * kC + c];
        }
        __syncthreads();
        if (tid < 64) {
            float s = 0.f;
            #pragma unroll
            for (int c = 0; c < kC; ++c) s += t[tid][c] * W_cd[c];
            Wt[(size_t)kC * kH + k0 + tid] = (bf16)s;
        }
    } else {
        if (tid < 64) {
            float v = b_ct[tid] * W_cd[tid];
            #pragma unroll
            for (int m = 1; m < 64; m <<= 1) v += __shfl_xor(v, m);
            if (tid == 0) bsc[0] = v + b_cd[0];
        }
    }
}

// ---- issue one A-chunk (128 rows x 256 B) via global_load_lds, src pre-swizzled ----
// 8 waves x 4 spans each (identical per-wave issue count to R7). Element (row,k)
// lands at byte row*256 + ((k*4) ^ ((row&7)<<4)); readers apply the same XOR.
__device__ __forceinline__ void issue_a(const float* __restrict__ hs_blk, int q,
                                        float* __restrict__ buf, int wv, int lane) {
    #pragma unroll
    for (int r = 0; r < 4; ++r) {
        const int span   = wv * 4 + r;            // 0..31, 4 rows (1 KB) per issue
        const int absrow = span * 4 + (lane >> 4);
        const int colB   = (lane & 15) * 16;
        const int scol   = colB ^ ((absrow & 7) << 4);
        const char* src  = (const char*)(hs_blk + (size_t)absrow * kH + q * kCK) + scol;
        float* dst = buf + span * 256;            // wave-uniform
        __builtin_amdgcn_global_load_lds(
            (const __attribute__((address_space(1))) void*)src,
            (__attribute__((address_space(3))) void*)dst, 16, 0, 0);
    }
}

// ---------- main: (32768 x 768) @ (768 x 65) bf16 MFMA ----------
// R7 schedule at kTB=128: 8 waves, each its OWN 16-token tile (no n-split, no
// cross-wave reduction). B staged once per chunk per block -> B traffic halves
// to 25.6 MB chip-wide. 73.4 KB LDS -> 2 blocks/CU = 16 waves/CU.
__global__ __launch_bounds__(512, 2) void incong_main(
    const float* __restrict__ hs,      // [kTokens][kH] f32
    const bf16*  __restrict__ Wt,      // [65][kH] bf16
    const float* __restrict__ bsc_p,
    const float* __restrict__ b_e1,
    const float* __restrict__ W_e2,
    const float* __restrict__ b_e2,
    float* __restrict__ out)           // [3][kTokens]
{
    __shared__ float lds_a[2][kTB][kCK];   // 2 x 32 KB, rows 256 B, no pad (swizzled)
    __shared__ bf16  lds_w[65][kBW];       // 9.4 KB

    const int tid  = threadIdx.x;
    const int lane = tid & 63;
    const int wv   = tid >> 6;         // 0..7: 16-token tile within block
    const int r16  = lane & 15;
    const int kg   = lane >> 4;        // 0..3

    const int tok0 = blockIdx.x * kTB;
    const float* hs_blk = hs + (size_t)tok0 * kH;

    f32x4 acc[5];
    #pragma unroll
    for (int n = 0; n < 5; ++n) acc[n] = (f32x4){0.f, 0.f, 0.f, 0.f};

    const int      trow  = wv * 16 + r16;
    const unsigned sw    = (unsigned)((r16 & 7) << 4);
    const char*    ab0   = (const char*)&lds_a[0][trow][0];
    const char*    ab1   = (const char*)&lds_a[1][trow][0];

    issue_a(hs_blk, 0, &lds_a[0][0][0], wv, lane);     // prologue: A(0) in flight

    for (int q = 0; q < kNQ; ++q) {
        const int pb = q & 1;
        // ---- stage B chunk q: 512 thr cover rows 0..63 (1 bf16x8 each), tid<8
        //      add row 64. Compiler's vmcnt before the ds_write drains A(q)
        //      exactly, leaving A(q+1) outstanding. ----
        {
            const int row0 = tid >> 3, col0 = (tid & 7) * 8;
            bf16x8 v0 = *reinterpret_cast<const bf16x8*>(&Wt[(size_t)row0 * kH + q * kCK + col0]);
            bf16x8 v2;
            if (tid < 8) v2 = *reinterpret_cast<const bf16x8*>(&Wt[(size_t)64 * kH + q * kCK + tid * 8]);
            if (q + 1 < kNQ) issue_a(hs_blk, q + 1, &lds_a[pb ^ 1][0][0], wv, lane);
            *reinterpret_cast<bf16x8*>(&lds_w[row0][col0]) = v0;
            if (tid < 8) *reinterpret_cast<bf16x8*>(&lds_w[64][tid * 8]) = v2;
        }
        asm volatile("s_waitcnt lgkmcnt(0)" ::: "memory");
        __builtin_amdgcn_s_barrier();
        asm volatile("" ::: "memory");

        // ---- compute chunk q: swizzled A reads + MFMA ----
        const char* abase = pb ? ab1 : ab0;
        #pragma unroll
        for (int s = 0; s < 2; ++s) {
            const unsigned o = (unsigned)(s * 128 + kg * 32);
            const f32x4 a0 = *reinterpret_cast<const f32x4*>(abase + (o ^ sw));
            const f32x4 a1 = *reinterpret_cast<const f32x4*>(abase + ((o + 16u) ^ sw));
            bf16x8 af;
            af[0] = (bf16)a0[0]; af[1] = (bf16)a0[1]; af[2] = (bf16)a0[2]; af[3] = (bf16)a0[3];
            af[4] = (bf16)a1[0]; af[5] = (bf16)a1[1]; af[6] = (bf16)a1[2]; af[7] = (bf16)a1[3];
            #pragma unroll
            for (int n = 0; n < 4; ++n) {
                const bf16x8 bfr = *reinterpret_cast<const bf16x8*>(
                    &lds_w[n * 16 + r16][s * 32 + kg * 8]);
                acc[n] = __builtin_amdgcn_mfma_f32_16x16x32_bf16(af, bfr, acc[n], 0, 0, 0);
            }
            {
                const bf16x8 b4 = *reinterpret_cast<const bf16x8*>(&lds_w[64][s * 32 + kg * 8]);
                acc[4] = __builtin_amdgcn_mfma_f32_16x16x32_bf16(af, b4, acc[4], 0, 0, 0);
            }
        }
        asm volatile("" ::: "memory");
        __builtin_amdgcn_s_barrier();      // all waves done reading before next overwrite
    }

    // ---- epilogue (per wave; D layout: col = lane&15, row = kg*4 + reg) ----
    float part[4] = {0.f, 0.f, 0.f, 0.f};
    #pragma unroll
    for (int n = 0; n < 4; ++n) {
        const int cidx = n * 16 + r16;
        const float be = b_e1[cidx];
        const float we = W_e2[cidx];
        #pragma unroll
        for (int r = 0; r < 4; ++r)
            part[r] += fmaxf(acc[n][r] + be, 0.f) * we;
    }
    #pragma unroll
    for (int m = 1; m < 16; m <<= 1) {
        #pragma unroll
        for (int r = 0; r < 4; ++r) part[r] += __shfl_xor(part[r], m);
    }
    if (r16 == 0) {
        const float bsc = bsc_p[0];
        const float be2 = b_e2[0];
        #pragma unroll
        for (int r = 0; r < 4; ++r) {
            const int tok = tok0 + wv * 16 + kg * 4 + r;
            const float sc = acc[4][r] + bsc;          // sc column accumulator
            out[tok]               = 1.f / (1.f + __expf(-sc));
            out[kTokens + tok]     = 1.f / (1.f + __expf(-(part[r] + be2)));
            out[2 * kTokens + tok] = 1.f / 4096.f;     // mean of softmax == 1/S
        }
    }
}

extern "C" void kernel_launch(void* const* d_in, const int* in_sizes, int n_in,
                              void* d_out, int out_size, void* d_ws, size_t ws_size,
                              hipStream_t stream) {
    const float* hs   = (const float*)d_in[0];
    // d_in[1] = attention_mask (all ones, unused by the reference math)
    const float* W_ct = (const float*)d_in[2];
    const float* b_ct = (const float*)d_in[3];
    const float* W_cd = (const float*)d_in[4];
    const float* b_cd = (const float*)d_in[5];
    const float* W_e1 = (const float*)d_in[6];
    const float* b_e1 = (const float*)d_in[7];
    const float* W_e2 = (const float*)d_in[8];
    const float* b_e2 = (const float*)d_in[9];
    // d_in[10..13] = W_q, b_q, W_k, b_k — unused (surprise is exactly 1/S)

    bf16*  Wt  = (bf16*)d_ws;
    float* bsc = (float*)((char*)d_ws + (size_t)80 * kH * sizeof(bf16));

    prep_kernel<<<25, 256, 0, stream>>>(W_ct, b_ct, W_cd, b_cd, W_e1, Wt, bsc);

    incong_main<<<kTokens / kTB, 512, 0, stream>>>(
        hs, Wt, bsc, b_e1, W_e2, b_e2, (float*)d_out);
}

// Round 13
// 27.648 us; speedup vs baseline: 1.6852x; 1.0916x over previous
//
#include <hip/hip_runtime.h>
#include <hip/hip_bf16.h>
#include <math.h>

typedef __bf16 bf16;
typedef __bf16 bf16x8 __attribute__((ext_vector_type(8)));
typedef float  f32x4  __attribute__((ext_vector_type(4)));

static constexpr int kTokens = 32768;   // B*S = 8*4096
static constexpr int kH   = 768;
static constexpr int kC   = 64;
static constexpr int kCK  = 64;         // K-chunk (A rows = 256 B, power of 2)
static constexpr int kNQ  = kH / kCK;   // 12 chunks
static constexpr int kTB  = 64;         // tokens per block (4 waves x 16)
static constexpr int kBW  = 72;         // B lds row stride (144 B == 16 mod 128: balanced)

// ---------- prep (all-coalesced): Wt[n][k]=W_e1^T, row 64 = w_sc = W_ct@W_cd ----------
__global__ __launch_bounds__(256) void prep_kernel(
    const float* __restrict__ W_ct, const float* __restrict__ b_ct,
    const float* __restrict__ W_cd, const float* __restrict__ b_cd,
    const float* __restrict__ W_e1, bf16* __restrict__ Wt,
    float* __restrict__ bsc) {
    __shared__ float t[64][65];
    const int tid = threadIdx.x;
    const int b   = blockIdx.x;
    if (b < 12) {
        const int k0 = b * 64;
        #pragma unroll
        for (int i = 0; i < 16; ++i) {
            int idx = tid + i * 256;
            int k = idx >> 6, n = idx & 63;
            t[k][n] = W_e1[(size_t)(k0 + k) * kC + n];
        }
        __syncthreads();
        #pragma unroll
        for (int i = 0; i < 16; ++i) {
            int idx = tid + i * 256;
            int n = idx >> 6, k = idx & 63;
            Wt[(size_t)n * kH + k0 + k] = (bf16)t[k][n];
        }
    } else if (b < 24) {
        const int k0 = (b - 12) * 64;
        #pragma unroll
        for (int i = 0; i < 16; ++i) {
            int idx = tid + i * 256;
            int k = idx >> 6, c = idx & 63;
            t[k][c] = W_ct[(size_t)(k0 + k) * kC + c];
        }
        __syncthreads();
        if (tid < 64) {
            float s = 0.f;
            #pragma unroll
            for (int c = 0; c < kC; ++c) s += t[tid][c] * W_cd[c];
            Wt[(size_t)kC * kH + k0 + tid] = (bf16)s;
        }
    } else {
        if (tid < 64) {
            float v = b_ct[tid] * W_cd[tid];
            #pragma unroll
            for (int m = 1; m < 64; m <<= 1) v += __shfl_xor(v, m);
            if (tid == 0) bsc[0] = v + b_cd[0];
        }
    }
}

// ---- issue one A-chunk (64 rows x 256 B) via global_load_lds, src pre-swizzled ----
// LDS dest is linear (wave-uniform base + lane*16); element (row,k) of the chunk ends
// up at byte (row*256) + ((k*4) ^ ((row&7)<<4)); readers apply the same XOR.
__device__ __forceinline__ void issue_a(const float* __restrict__ hs_blk, int q,
                                        float* __restrict__ buf, int wv, int lane) {
    #pragma unroll
    for (int r = 0; r < 4; ++r) {
        const int span   = wv * 4 + r;            // 0..15, 4 rows (1 KB) per issue
        const int absrow = span * 4 + (lane >> 4);
        const int colB   = (lane & 15) * 16;
        const int scol   = colB ^ ((absrow & 7) << 4);
        const char* src  = (const char*)(hs_blk + (size_t)absrow * kH + q * kCK) + scol;
        float* dst = buf + span * 256;            // wave-uniform
        __builtin_amdgcn_global_load_lds(
            (const __attribute__((address_space(1))) void*)src,
            (__attribute__((address_space(3))) void*)dst, 16, 0, 0);
    }
}

// ---------- main: (32768 x 768) @ (768 x 65) bf16 MFMA ----------
// A: f32 direct-to-LDS (global_load_lds, XOR-swizzled, double-buffered chunks).
// B: 65x64 bf16 chunk re-staged per K-chunk (L2-resident). Raw barriers + the
// compiler's own counted vmcnt keep the next A-chunk in flight across the barrier.
__global__ __launch_bounds__(256, 3) void incong_main(
    const float* __restrict__ hs,      // [kTokens][kH] f32
    const bf16*  __restrict__ Wt,      // [65][kH] bf16
    const float* __restrict__ bsc_p,
    const float* __restrict__ b_e1,
    const float* __restrict__ W_e2,
    const float* __restrict__ b_e2,
    float* __restrict__ out)           // [3][kTokens]
{
    __shared__ float lds_a[2][kTB][kCK];   // 2 x 16 KB, rows 256 B, no pad (swizzled)
    __shared__ bf16  lds_w[65][kBW];       // 9.4 KB

    const int tid  = threadIdx.x;
    const int lane = tid & 63;
    const int wv   = tid >> 6;         // 0..3: 16-token tile within block
    const int r16  = lane & 15;
    const int kg   = lane >> 4;        // 0..3

    const int tok0 = blockIdx.x * kTB;
    const float* hs_blk = hs + (size_t)tok0 * kH;

    f32x4 acc[5];
    #pragma unroll
    for (int n = 0; n < 5; ++n) acc[n] = (f32x4){0.f, 0.f, 0.f, 0.f};

    const int      trow  = wv * 16 + r16;
    const unsigned sw    = (unsigned)((r16 & 7) << 4);
    const char*    ab0   = (const char*)&lds_a[0][trow][0];
    const char*    ab1   = (const char*)&lds_a[1][trow][0];

    issue_a(hs_blk, 0, &lds_a[0][0][0], wv, lane);     // prologue: A(0) in flight

    for (int q = 0; q < kNQ; ++q) {
        const int b = q & 1;
        // ---- stage B chunk q (loads then writes; compiler's vmcnt before the
        //      ds_write drains A(q) exactly, leaving A(q+1) outstanding) ----
        {
            const int c0 = tid, c1 = tid + 256;
            const int row0 = c0 >> 3, col0 = (c0 & 7) * 8;
            const int row1 = c1 >> 3, col1 = (c1 & 7) * 8;
            bf16x8 v0 = *reinterpret_cast<const bf16x8*>(&Wt[(size_t)row0 * kH + q * kCK + col0]);
            bf16x8 v1 = *reinterpret_cast<const bf16x8*>(&Wt[(size_t)row1 * kH + q * kCK + col1]);
            bf16x8 v2;
            if (tid < 8) v2 = *reinterpret_cast<const bf16x8*>(&Wt[(size_t)64 * kH + q * kCK + tid * 8]);
            if (q + 1 < kNQ) issue_a(hs_blk, q + 1, &lds_a[b ^ 1][0][0], wv, lane);
            *reinterpret_cast<bf16x8*>(&lds_w[row0][col0]) = v0;
            *reinterpret_cast<bf16x8*>(&lds_w[row1][col1]) = v1;
            if (tid < 8) *reinterpret_cast<bf16x8*>(&lds_w[64][tid * 8]) = v2;
        }
        asm volatile("s_waitcnt lgkmcnt(0)" ::: "memory");
        __builtin_amdgcn_s_barrier();
        asm volatile("" ::: "memory");

        // ---- compute chunk q: swizzled A reads + MFMA ----
        const char* abase = b ? ab1 : ab0;
        #pragma unroll
        for (int s = 0; s < 2; ++s) {
            const unsigned o = (unsigned)(s * 128 + kg * 32);
            const f32x4 a0 = *reinterpret_cast<const f32x4*>(abase + (o ^ sw));
            const f32x4 a1 = *reinterpret_cast<const f32x4*>(abase + ((o + 16u) ^ sw));
            bf16x8 af;
            af[0] = (bf16)a0[0]; af[1] = (bf16)a0[1]; af[2] = (bf16)a0[2]; af[3] = (bf16)a0[3];
            af[4] = (bf16)a1[0]; af[5] = (bf16)a1[1]; af[6] = (bf16)a1[2]; af[7] = (bf16)a1[3];
            #pragma unroll
            for (int n = 0; n < 4; ++n) {
                const bf16x8 bfr = *reinterpret_cast<const bf16x8*>(
                    &lds_w[n * 16 + r16][s * 32 + kg * 8]);
                acc[n] = __builtin_amdgcn_mfma_f32_16x16x32_bf16(af, bfr, acc[n], 0, 0, 0);
            }
            {
                const bf16x8 b4 = *reinterpret_cast<const bf16x8*>(&lds_w[64][s * 32 + kg * 8]);
                acc[4] = __builtin_amdgcn_mfma_f32_16x16x32_bf16(af, b4, acc[4], 0, 0, 0);
            }
        }
        asm volatile("" ::: "memory");
        __builtin_amdgcn_s_barrier();      // all waves done reading before next overwrite
    }

    // ---- epilogue (per wave; D layout: col = lane&15, row = kg*4 + reg) ----
    float part[4] = {0.f, 0.f, 0.f, 0.f};
    #pragma unroll
    for (int n = 0; n < 4; ++n) {
        const int cidx = n * 16 + r16;
        const float be = b_e1[cidx];
        const float we = W_e2[cidx];
        #pragma unroll
        for (int r = 0; r < 4; ++r)
            part[r] += fmaxf(acc[n][r] + be, 0.f) * we;
    }
    #pragma unroll
    for (int m = 1; m < 16; m <<= 1) {
        #pragma unroll
        for (int r = 0; r < 4; ++r) part[r] += __shfl_xor(part[r], m);
    }
    if (r16 == 0) {
        const float bsc = bsc_p[0];
        const float be2 = b_e2[0];
        #pragma unroll
        for (int r = 0; r < 4; ++r) {
            const int tok = tok0 + wv * 16 + kg * 4 + r;
            const float sc = acc[4][r] + bsc;          // sc column accumulator
            out[tok]               = 1.f / (1.f + __expf(-sc));
            out[kTokens + tok]     = 1.f / (1.f + __expf(-(part[r] + be2)));
            out[2 * kTokens + tok] = 1.f / 4096.f;     // mean of softmax == 1/S
        }
    }
}

extern "C" void kernel_launch(void* const* d_in, const int* in_sizes, int n_in,
                              void* d_out, int out_size, void* d_ws, size_t ws_size,
                              hipStream_t stream) {
    const float* hs   = (const float*)d_in[0];
    // d_in[1] = attention_mask (all ones, unused by the reference math)
    const float* W_ct = (const float*)d_in[2];
    const float* b_ct = (const float*)d_in[3];
    const float* W_cd = (const float*)d_in[4];
    const float* b_cd = (const float*)d_in[5];
    const float* W_e1 = (const float*)d_in[6];
    const float* b_e1 = (const float*)d_in[7];
    const float* W_e2 = (const float*)d_in[8];
    const float* b_e2 = (const float*)d_in[9];
    // d_in[10..13] = W_q, b_q, W_k, b_k — unused (surprise is exactly 1/S)

    bf16*  Wt  = (bf16*)d_ws;
    float* bsc = (float*)((char*)d_ws + (size_t)80 * kH * sizeof(bf16));

    prep_kernel<<<25, 256, 0, stream>>>(W_ct, b_ct, W_cd, b_cd, W_e1, Wt, bsc);

    incong_main<<<kTokens / kTB, 256, 0, stream>>>(
        hs, Wt, bsc, b_e1, W_e2, b_e2, (float*)d_out);
}